// Round 8
// baseline (247.999 us; speedup 1.0000x reference)
//
#include <hip/hip_runtime.h>

// GatedDeltaNet fused kernel for MI355X (gfx950) — R13.
// R12 (TBS=64, 100.5 us) confirmed the phase-latency theory: bigger tiles +
// fewer barriers/element + full MFMA units win; occupancy% is not the metric.
// R13 doubles again: TBS=128, 1024 threads (16 waves), 1 block/CU, LDS 134 KB.
// Per-thread ILP unchanged (2 rows in A/C/E); Stage B = 46 full 32-row
// m-units flat-assigned 3-per-wave; barrier events per element halved again.

#define TBS 128
#define ROWS 130         // TBS + 2 halo
#define DD 64
#define T_LEN 4096
#define TILES_PB 32      // T_LEN / TBS
#define LSTRIDE 72       // ushort stride: 144 B = 16B-aligned, 2-way bank alias (free)

typedef unsigned short ushort_t;
typedef short bf16x8 __attribute__((ext_vector_type(8)));
typedef float f32x4 __attribute__((ext_vector_type(4)));
typedef float f32x16 __attribute__((ext_vector_type(16)));

__device__ inline float lo2f(unsigned u) { return __uint_as_float(u << 16); }
__device__ inline float hi2f(unsigned u) { return __uint_as_float(u & 0xffff0000u); }
__device__ inline unsigned pk2(float a, float b) {    // bf16(a) lo16, bf16(b) hi16, RNE
    unsigned r;
    asm("v_cvt_pk_bf16_f32 %0, %1, %2" : "=v"(r) : "v"(a), "v"(b));
    return r;
}
__device__ inline ushort_t f2b(float f) {             // scalar RNE (cvt_kernel only)
    unsigned u = __float_as_uint(f);
    u += 0x7fffu + ((u >> 16) & 1u);
    return (ushort_t)(u >> 16);
}

// HW approx (~1 ulp) — avoids IEEE div/rsqrt expansions (no -ffast-math here).
__device__ inline float rcp_(float x) {
#if __has_builtin(__builtin_amdgcn_rcpf)
    return __builtin_amdgcn_rcpf(x);
#else
    float r; asm("v_rcp_f32 %0, %1" : "=v"(r) : "v"(x)); return r;
#endif
}
__device__ inline float rsq_(float x) {
#if __has_builtin(__builtin_amdgcn_rsqf)
    return __builtin_amdgcn_rsqf(x);
#else
    float r; asm("v_rsq_f32 %0, %1" : "=v"(r) : "v"(x)); return r;
#endif
}

// 16-lane sum broadcast via DPP row_ror (full-rate VALU, no DS pipe).
template<int CTRL>
__device__ inline float dpp_add(float v) {
    int t = __builtin_amdgcn_mov_dpp(__float_as_int(v), CTRL, 0xf, 0xf, true);
    return v + __int_as_float(t);
}
__device__ inline float sum16(float v) {
    v = dpp_add<0x128>(v);   // row_ror:8
    v = dpp_add<0x124>(v);   // row_ror:4
    v = dpp_add<0x122>(v);   // row_ror:2
    v = dpp_add<0x121>(v);   // row_ror:1
    return v;
}

__device__ inline float sigmoidf_(float x) { return rcp_(1.f + __expf(-x)); }
__device__ inline float tanhf_(float x) {
    float xc = fminf(fmaxf(x, -15.f), 15.f);
    float e2 = __expf(2.f * xc);
    return (e2 - 1.f) * rcp_(e2 + 1.f);
}

// ---- pre-pass: fp32 -> bf16 pack of the six 64x64 weight matrices ----------
// ushort layout: qw 0, kw 4096, vw 8192, aw 12288, bw 16384, pw 20480
__global__ __launch_bounds__(256) void cvt_kernel(
    const float* __restrict__ w0, const float* __restrict__ w1,
    const float* __restrict__ w2, const float* __restrict__ w3,
    const float* __restrict__ w4, const float* __restrict__ w5,
    ushort_t* __restrict__ dst) {
    int i = blockIdx.x * 256 + threadIdx.x;            // < 24576
    const float* ws_[6] = {w0, w1, w2, w3, w4, w5};
    dst[i] = f2b(ws_[i >> 12][i & 4095]);
}

// One 32x32 GEMM strip: D[o][t] = sum_k W[o][k]*act[t][k] + bias[o]
// o in [strip*32, strip*32+32), t in [m0, m0+32).
// A-frag (W): m=lane&31 -> o, k=(lane>>5)*8+j.  B-frag (act): n=lane&31 -> t.
// C/D: col(lane&31)=t, row=(reg&3)+8*(reg>>2)+4*(lane>>5) -> o.
__device__ inline void mm32(const ushort_t* __restrict__ W,
                            const float* __restrict__ bias,
                            const ushort_t* src, ushort_t* dst,
                            int m0, int strip, int lane) {
    const int l31  = lane & 31;
    const int half = lane >> 5;
    const int t    = m0 + l31;
    const ushort_t* wrow = W + (strip * 32 + l31) * 64 + half * 8;
    const ushort_t* arow = src + t * LSTRIDE + half * 8;
    f32x16 acc = {};
#pragma unroll
    for (int kk = 0; kk < 4; kk++) {
        bf16x8 af = *(const bf16x8*)(wrow + kk * 16);
        bf16x8 bf = *(const bf16x8*)(arow + kk * 16);
        acc = __builtin_amdgcn_mfma_f32_32x32x16_bf16(af, bf, acc, 0, 0, 0);
    }
#pragma unroll
    for (int rg = 0; rg < 4; rg++) {
        const int o0 = strip * 32 + rg * 8 + half * 4;
        f32x4 bv = *(const f32x4*)(bias + o0);
        uint2 w;
        w.x = pk2(acc[rg * 4 + 0] + bv[0], acc[rg * 4 + 1] + bv[1]);
        w.y = pk2(acc[rg * 4 + 2] + bv[2], acc[rg * 4 + 3] + bv[3]);
        *(uint2*)(dst + t * LSTRIDE + o0) = w;
    }
}

// conv3 (zero-pad) + sigmoid on 4 channels of row rr from bf16 buffer F.
__device__ inline void conv_sig4(const float* __restrict__ CW,
                                 const float* __restrict__ CB, int cb,
                                 const ushort_t* F, int rr, bool zl, bool zr,
                                 float out[4]) {
    uint2 m_ = *(const uint2*)(F + (rr - 1) * LSTRIDE + cb);
    uint2 c_ = *(const uint2*)(F + rr * LSTRIDE + cb);
    uint2 p_ = *(const uint2*)(F + (rr + 1) * LSTRIDE + cb);
    f32x4 w0 = *(const f32x4*)(CW + cb);
    f32x4 w1 = *(const f32x4*)(CW + 64 + cb);
    f32x4 w2 = *(const f32x4*)(CW + 128 + cb);
    f32x4 bb = *(const f32x4*)(CB + cb);
    float xm[4] = {lo2f(m_.x), hi2f(m_.x), lo2f(m_.y), hi2f(m_.y)};
    float x0[4] = {lo2f(c_.x), hi2f(c_.x), lo2f(c_.y), hi2f(c_.y)};
    float xp[4] = {lo2f(p_.x), hi2f(p_.x), lo2f(p_.y), hi2f(p_.y)};
#pragma unroll
    for (int i = 0; i < 4; i++) {
        float a = fmaf(w0[i], zl ? 0.f : xm[i],
                  fmaf(w1[i], x0[i],
                  fmaf(w2[i], zr ? 0.f : xp[i], bb[i])));
        out[i] = sigmoidf_(a);
    }
}

__global__ __launch_bounds__(1024, 4) void gdn_kernel(
    const float* __restrict__ xg, const float* __restrict__ norm_g,
    const ushort_t* __restrict__ wpack,
    const float* __restrict__ qcw, const float* __restrict__ qcb,
    const float* __restrict__ kcw, const float* __restrict__ kcb,
    const float* __restrict__ vcw, const float* __restrict__ vcb,
    const float* __restrict__ qbf, const float* __restrict__ kbf,
    const float* __restrict__ vbf, const float* __restrict__ abf,
    const float* __restrict__ bbf, const float* __restrict__ pbf,
    const float* __restrict__ post_g,
    float* __restrict__ outg) {
    __shared__ __align__(16) ushort_t Xs[ROWS * LSTRIDE];   // bf16 x rows t0-1..t0+128
    __shared__ __align__(16) ushort_t Hs[ROWS * LSTRIDE];   // h; rows 1..128 become Ns
    __shared__ __align__(16) ushort_t Fq[ROWS * LSTRIDE];   // qlin; later dhat rows 1..128
    __shared__ __align__(16) ushort_t Fk[ROWS * LSTRIDE];
    __shared__ __align__(16) ushort_t Fv[ROWS * LSTRIDE];
    __shared__ __align__(16) ushort_t Fa[ROWS * LSTRIDE];
    __shared__ __align__(16) ushort_t Fb[ROWS * LSTRIDE];
    __shared__ __align__(16) float CWs[768];
    // CWs: [0..191] q taps (tap-major [3][64]); [192..383] k; [384..575] v;
    //      [576] qcb; [640] kcb; [704] vcb

    const int tid    = threadIdx.x;
    const int wave   = tid >> 6;         // 0..15
    const int lane   = tid & 63;
    const int cb     = (tid & 15) * 4;   // channel base (4 ch/lane)
    const int rgrp   = tid >> 4;         // 0..63
    const int bidx = blockIdx.x;
    const int b    = bidx >> 5;          // / TILES_PB (=32)
    const int tile = bidx & (TILES_PB - 1);
    const int t0   = tile * TBS;
    const bool left_edge  = (t0 == 0);
    const bool right_edge = (t0 + TBS >= T_LEN);

    // ---- Stage A: x from global; zc_rmsnorm in-register; Xs+Hs bf16 --------
    // One-pass mean/var.  Rows rgrp, rgrp+64; extra rows 128,129 on rgrp
    // 16,17.  Edge halo rows write exact zeros.
    {
        const f32x4 gv = *(const f32x4*)(norm_g + cb);
        auto do_row = [&](int r) {
            int t = t0 + r - 1;
            f32x4 xv = {0.f, 0.f, 0.f, 0.f};
            if (t >= 0 && t < T_LEN)
                xv = *(const f32x4*)(xg + ((size_t)b * T_LEN + t) * DD + cb);
            float s  = (xv[0] + xv[1]) + (xv[2] + xv[3]);
            float s2 = 0.f;
#pragma unroll
            for (int i = 0; i < 4; i++) s2 = fmaf(xv[i], xv[i], s2);
            s = sum16(s); s2 = sum16(s2);
            float mean = s * (1.f / 64.f);
            float var  = fmaxf(fmaf(-mean, mean, s2 * (1.f / 64.f)), 0.f);
            float inv  = rsq_(var + 1e-8f);
            uint2 xpk; xpk.x = pk2(xv[0], xv[1]); xpk.y = pk2(xv[2], xv[3]);
            *(uint2*)(Xs + r * LSTRIDE + cb) = xpk;
            uint2 hpk;
            hpk.x = pk2((xv[0] - mean) * inv * gv[0], (xv[1] - mean) * inv * gv[1]);
            hpk.y = pk2((xv[2] - mean) * inv * gv[2], (xv[3] - mean) * inv * gv[3]);
            *(uint2*)(Hs + r * LSTRIDE + cb) = hpk;
        };
        do_row(rgrp);
        do_row(rgrp + 64);
        if (rgrp == 16 || rgrp == 17) do_row(rgrp + 112);  // rows 128,129
    }
    // conv taps + biases -> CWs (tap-major)
    if (tid < 192) {
        int tap = tid >> 6, c = tid & 63;
        CWs[tid]       = qcw[c * 3 + tap];
        CWs[192 + tid] = kcw[c * 3 + tap];
        CWs[384 + tid] = vcw[c * 3 + tap];
    } else if (tid < 256) {
        int c = tid - 192;
        CWs[576 + c] = qcb[c];
        CWs[640 + c] = kcb[c];
        CWs[704 + c] = vcb[c];
    }
    __syncthreads();

    // ---- Stage B: 46 full 32-row m-units over 16 waves (<=3 each) ----------
    // u<30:  q/k/v: g=u/10, r=u%10, strip=r&1, m0=m0tab[r>>1] (98-unit
    //        overlaps 96-unit on rows 98..127 — identical values, benign).
    // u>=30: a/b:   j=u-30, g=j>>3, r=j&7, strip=r&1, m0=1+32*(r>>1).
    {
        const int m0tab[5] = {0, 32, 64, 96, 98};
#pragma unroll
        for (int i = 0; i < 3; i++) {
            const int u = wave + 16 * i;
            if (u >= 46) break;
            const ushort_t* W; const float* bias; const ushort_t* src; ushort_t* dst;
            int m0, strip;
            if (u < 30) {
                const int g = u / 10, r = u % 10;
                W = wpack + g * 4096;
                bias = (g == 0) ? qbf : (g == 1) ? kbf : vbf;
                dst  = (g == 0) ? Fq  : (g == 1) ? Fk  : Fv;
                src = Hs;
                strip = r & 1;
                m0 = m0tab[r >> 1];
            } else {
                const int j = u - 30, g = j >> 3, r = j & 7;
                W = wpack + (3 + g) * 4096;
                bias = g ? bbf : abf;
                dst  = g ? Fb  : Fa;
                src = Xs;
                strip = r & 1;
                m0 = 1 + 32 * (r >> 1);
            }
            mm32(W, bias, src, dst, m0, strip, lane);
        }
    }
    __syncthreads();

    // ---- Stage C: conv+sig (q,k,v), l2norm(q,k), delta, gate, post-norm ----
    // Two independent rows per thread (rr, rr+64) -> 2x ILP on the longest
    // dependency chain.
#pragma unroll
    for (int half_t = 0; half_t < 2; half_t++) {
        const int rr = rgrp + 1 + half_t * 64;  // 1..64, 65..128
        const bool zl = (rr == 1) && left_edge;
        const bool zr = (rr == TBS) && right_edge;
        float qs[4], ks[4], vs[4];
        conv_sig4(CWs,       CWs + 576, cb, Fq, rr, zl, zr, qs);
        conv_sig4(CWs + 192, CWs + 640, cb, Fk, rr, zl, zr, ks);
        conv_sig4(CWs + 384, CWs + 704, cb, Fv, rr, zl, zr, vs);
        float sq = 0.f, sk = 0.f;
#pragma unroll
        for (int i = 0; i < 4; i++) {
            sq = fmaf(qs[i], qs[i], sq);
            sk = fmaf(ks[i], ks[i], sk);
        }
        float qi = rsq_(sum16(sq) + 1e-8f);
        float ki = rsq_(sum16(sk) + 1e-8f);
        uint2 av = *(const uint2*)(Fa + rr * LSTRIDE + cb);
        uint2 bv = *(const uint2*)(Fb + rr * LSTRIDE + cb);
        float af[4] = {lo2f(av.x), hi2f(av.x), lo2f(av.y), hi2f(av.y)};
        float bf[4] = {lo2f(bv.x), hi2f(bv.x), lo2f(bv.y), hi2f(bv.y)};
        float d2[4]; float sm = 0.f, sm2 = 0.f;
#pragma unroll
        for (int i = 0; i < 4; i++) {
            float delta = (qs[i] * qi) * (ks[i] * ki) * vs[i];
            d2[i] = fmaf(tanhf_(af[i]), delta, bf[i]);
            sm += d2[i];
            sm2 = fmaf(d2[i], d2[i], sm2);
        }
        sm = sum16(sm); sm2 = sum16(sm2);
        float mean = sm * (1.f / 64.f);
        float var  = fmaxf(fmaf(-mean, mean, sm2 * (1.f / 64.f)), 0.f);
        float inv  = rsq_(var + 1e-8f);
        const f32x4 pgv = *(const f32x4*)(post_g + cb);
        uint2 npk;
        npk.x = pk2((d2[0] - mean) * inv * pgv[0], (d2[1] - mean) * inv * pgv[1]);
        npk.y = pk2((d2[2] - mean) * inv * pgv[2], (d2[3] - mean) * inv * pgv[3]);
        *(uint2*)(Hs + rr * LSTRIDE + cb) = npk;   // Ns into Hs rows 1..128
    }
    __syncthreads();

    // ---- Stage D: dhat = Ns @ pw^T + pb, 8 units on waves 0..7 -------------
    if (wave < 8)
        mm32(wpack + 5 * 4096, pbf, Hs, Fq, 1 + 32 * (wave >> 1), wave & 1, lane);
    __syncthreads();

    // ---- Stage E: out = x + sigmoid(silu(dhat))*dhat (fully coalesced) -----
#pragma unroll
    for (int half_t = 0; half_t < 2; half_t++) {
        const int tr = rgrp + half_t * 64;      // t-rel 0..127
        const int t  = t0 + tr;
        uint2 dpk = *(const uint2*)(Fq + (tr + 1) * LSTRIDE + cb);
        float dh[4] = {lo2f(dpk.x), hi2f(dpk.x), lo2f(dpk.y), hi2f(dpk.y)};
        const float* xrow = xg + ((size_t)b * T_LEN + t) * DD + cb;
        f32x4 xv = *(const f32x4*)(xrow);
        f32x4 ov;
#pragma unroll
        for (int i = 0; i < 4; i++) {
            float sl = dh[i] * sigmoidf_(dh[i]);
            ov[i] = xv[i] + sigmoidf_(sl) * dh[i];
        }
        *(f32x4*)(outg + ((size_t)b * T_LEN + t) * DD + cb) = ov;
    }
}

extern "C" void kernel_launch(void* const* d_in, const int* in_sizes, int n_in,
                              void* d_out, int out_size, void* d_ws, size_t ws_size,
                              hipStream_t stream) {
    const float* xg     = (const float*)d_in[0];
    const float* norm_g = (const float*)d_in[1];
    const float* qw  = (const float*)d_in[2];
    const float* qb  = (const float*)d_in[3];
    const float* kw  = (const float*)d_in[4];
    const float* kb  = (const float*)d_in[5];
    const float* vw  = (const float*)d_in[6];
    const float* vb  = (const float*)d_in[7];
    const float* qcw = (const float*)d_in[8];
    const float* qcb = (const float*)d_in[9];
    const float* kcw = (const float*)d_in[10];
    const float* kcb = (const float*)d_in[11];
    const float* vcw = (const float*)d_in[12];
    const float* vcb = (const float*)d_in[13];
    const float* aw  = (const float*)d_in[14];
    const float* ab  = (const float*)d_in[15];
    const float* bw  = (const float*)d_in[16];
    const float* bb  = (const float*)d_in[17];
    const float* pg  = (const float*)d_in[18];
    const float* pw  = (const float*)d_in[19];
    const float* pb  = (const float*)d_in[20];

    ushort_t* wpack = (ushort_t*)d_ws;

    hipLaunchKernelGGL(cvt_kernel, dim3(96), dim3(256), 0, stream,
                       qw, kw, vw, aw, bw, pw, wpack);

    const int B = in_sizes[0] / (T_LEN * DD);
    hipLaunchKernelGGL(gdn_kernel, dim3(B * TILES_PB), dim3(1024), 0, stream,
                       xg, norm_g, wpack, qcw, qcb, kcw, kcb, vcw, vcb,
                       qb, kb, vb, ab, bb, pb, pg,
                       (float*)d_out);
}

// Round 10
// 211.600 us; speedup vs baseline: 1.1720x; 1.1720x over previous
//
#include <hip/hip_runtime.h>

// GatedDeltaNet fused kernel for MI355X (gfx950) — R14 (resubmit; previous
// round was an infra failure, no data).
// Tile curve mapped: TBS 16->176, 32->122.7, 64->100.5 (R12), 128->134 (R13,
// 1 blk/CU barrier exposure).  R14 = R12 (TBS=64, 512 thr, 2 blk/CU) + two
// local phase-span cuts:
//  (1) Stage D spread over all 8 waves as 16 16x16 tiles (pm16_lds, verified
//      R9/R11) — was 4 waves x 4 serial MFMA with 4 waves idle.
//  (2) Stage A rows shifted +1 so each thread's rows == its Stage-E rows;
//      x kept in registers A->E (no E reload, no main-path bounds check).
//      Halo rows 0,65 on rgrp 16,20 (3-unit B-waves), Hs only.

#define TBS 64
#define ROWS 66          // TBS + 2 halo
#define DD 64
#define T_LEN 4096
#define TILES_PB 64      // T_LEN / TBS
#define LSTRIDE 72       // ushort stride: 144 B = 16B-aligned, 2-way bank alias (free)

typedef unsigned short ushort_t;
typedef short bf16x8 __attribute__((ext_vector_type(8)));
typedef float f32x4 __attribute__((ext_vector_type(4)));
typedef float f32x16 __attribute__((ext_vector_type(16)));

__device__ inline float lo2f(unsigned u) { return __uint_as_float(u << 16); }
__device__ inline float hi2f(unsigned u) { return __uint_as_float(u & 0xffff0000u); }
__device__ inline unsigned pk2(float a, float b) {    // bf16(a) lo16, bf16(b) hi16, RNE
    unsigned r;
    asm("v_cvt_pk_bf16_f32 %0, %1, %2" : "=v"(r) : "v"(a), "v"(b));
    return r;
}
__device__ inline ushort_t f2b(float f) {             // scalar RNE (cvt_kernel only)
    unsigned u = __float_as_uint(f);
    u += 0x7fffu + ((u >> 16) & 1u);
    return (ushort_t)(u >> 16);
}

// HW approx (~1 ulp) — avoids IEEE div/rsqrt expansions (no -ffast-math here).
__device__ inline float rcp_(float x) {
#if __has_builtin(__builtin_amdgcn_rcpf)
    return __builtin_amdgcn_rcpf(x);
#else
    float r; asm("v_rcp_f32 %0, %1" : "=v"(r) : "v"(x)); return r;
#endif
}
__device__ inline float rsq_(float x) {
#if __has_builtin(__builtin_amdgcn_rsqf)
    return __builtin_amdgcn_rsqf(x);
#else
    float r; asm("v_rsq_f32 %0, %1" : "=v"(r) : "v"(x)); return r;
#endif
}

// 16-lane sum broadcast via DPP row_ror (full-rate VALU, no DS pipe).
template<int CTRL>
__device__ inline float dpp_add(float v) {
    int t = __builtin_amdgcn_mov_dpp(__float_as_int(v), CTRL, 0xf, 0xf, true);
    return v + __int_as_float(t);
}
__device__ inline float sum16(float v) {
    v = dpp_add<0x128>(v);   // row_ror:8
    v = dpp_add<0x124>(v);   // row_ror:4
    v = dpp_add<0x122>(v);   // row_ror:2
    v = dpp_add<0x121>(v);   // row_ror:1
    return v;
}

__device__ inline float sigmoidf_(float x) { return rcp_(1.f + __expf(-x)); }
__device__ inline float tanhf_(float x) {
    float xc = fminf(fmaxf(x, -15.f), 15.f);
    float e2 = __expf(2.f * xc);
    return (e2 - 1.f) * rcp_(e2 + 1.f);
}

// ---- pre-pass: fp32 -> bf16 pack of the six 64x64 weight matrices ----------
// ushort layout: qw 0, kw 4096, vw 8192, aw 12288, bw 16384, pw 20480
__global__ __launch_bounds__(256) void cvt_kernel(
    const float* __restrict__ w0, const float* __restrict__ w1,
    const float* __restrict__ w2, const float* __restrict__ w3,
    const float* __restrict__ w4, const float* __restrict__ w5,
    ushort_t* __restrict__ dst) {
    int i = blockIdx.x * 256 + threadIdx.x;            // < 24576
    const float* ws_[6] = {w0, w1, w2, w3, w4, w5};
    dst[i] = f2b(ws_[i >> 12][i & 4095]);
}

// One 32x32 GEMM strip: D[o][t] = sum_k W[o][k]*act[t][k] + bias[o]
// o in [strip*32, strip*32+32), t in [m0, m0+32).
// A-frag (W): m=lane&31 -> o, k=(lane>>5)*8+j.  B-frag (act): n=lane&31 -> t.
// C/D: col(lane&31)=t, row=(reg&3)+8*(reg>>2)+4*(lane>>5) -> o.
__device__ inline void mm32(const ushort_t* __restrict__ W,
                            const float* __restrict__ bias,
                            const ushort_t* src, ushort_t* dst,
                            int m0, int strip, int lane) {
    const int l31  = lane & 31;
    const int half = lane >> 5;
    const int t    = m0 + l31;
    const ushort_t* wrow = W + (strip * 32 + l31) * 64 + half * 8;
    const ushort_t* arow = src + t * LSTRIDE + half * 8;
    f32x16 acc = {};
#pragma unroll
    for (int kk = 0; kk < 4; kk++) {
        bf16x8 af = *(const bf16x8*)(wrow + kk * 16);
        bf16x8 bf = *(const bf16x8*)(arow + kk * 16);
        acc = __builtin_amdgcn_mfma_f32_32x32x16_bf16(af, bf, acc, 0, 0, 0);
    }
#pragma unroll
    for (int rg = 0; rg < 4; rg++) {
        const int o0 = strip * 32 + rg * 8 + half * 4;
        f32x4 bv = *(const f32x4*)(bias + o0);
        uint2 w;
        w.x = pk2(acc[rg * 4 + 0] + bv[0], acc[rg * 4 + 1] + bv[1]);
        w.y = pk2(acc[rg * 4 + 2] + bv[2], acc[rg * 4 + 3] + bv[3]);
        *(uint2*)(dst + t * LSTRIDE + o0) = w;
    }
}

// One 16x16 p-GEMM tile -> LDS, K=64 via 2x mfma_f32_16x16x32_bf16.
// Mapping HW-verified in R9/R11.  A-frag (pw): row(lane&15)->o,
// k=(lane>>4)*8+j.  B-frag (Ns rows 1..64): col(lane&15)->t.
// C/D: col(lane&15)=t, row=(lane>>4)*4+reg -> o => per-lane f32x4 in o,
// packed to one uint2 LDS write at row t (t-rel 0..63).
__device__ inline void pm16_lds(const ushort_t* __restrict__ W,
                                const float* __restrict__ pbf,
                                const ushort_t* Ns, ushort_t* dst,
                                int s, int h, int lane) {
    const int l15 = lane & 15;
    const int kg  = lane >> 4;            // 0..3
    const ushort_t* wrow = W + (s * 16 + l15) * 64 + kg * 8;
    const ushort_t* arow = Ns + (1 + h * 16 + l15) * LSTRIDE + kg * 8;
    f32x4 acc = {};
#pragma unroll
    for (int kk = 0; kk < 2; kk++) {
        bf16x8 af = *(const bf16x8*)(wrow + kk * 32);
        bf16x8 bf = *(const bf16x8*)(arow + kk * 32);
        acc = __builtin_amdgcn_mfma_f32_16x16x32_bf16(af, bf, acc, 0, 0, 0);
    }
    const int t  = h * 16 + l15;          // t-rel 0..63
    const int o0 = s * 16 + kg * 4;
    f32x4 pv = *(const f32x4*)(pbf + o0);
    uint2 w;
    w.x = pk2(acc[0] + pv[0], acc[1] + pv[1]);
    w.y = pk2(acc[2] + pv[2], acc[3] + pv[3]);
    *(uint2*)(dst + t * LSTRIDE + o0) = w;
}

// conv3 (zero-pad) + sigmoid on 4 channels of row rr from bf16 buffer F.
__device__ inline void conv_sig4(const float* __restrict__ CW,
                                 const float* __restrict__ CB, int cb,
                                 const ushort_t* F, int rr, bool zl, bool zr,
                                 float out[4]) {
    uint2 m_ = *(const uint2*)(F + (rr - 1) * LSTRIDE + cb);
    uint2 c_ = *(const uint2*)(F + rr * LSTRIDE + cb);
    uint2 p_ = *(const uint2*)(F + (rr + 1) * LSTRIDE + cb);
    f32x4 w0 = *(const f32x4*)(CW + cb);
    f32x4 w1 = *(const f32x4*)(CW + 64 + cb);
    f32x4 w2 = *(const f32x4*)(CW + 128 + cb);
    f32x4 bb = *(const f32x4*)(CB + cb);
    float xm[4] = {lo2f(m_.x), hi2f(m_.x), lo2f(m_.y), hi2f(m_.y)};
    float x0[4] = {lo2f(c_.x), hi2f(c_.x), lo2f(c_.y), hi2f(c_.y)};
    float xp[4] = {lo2f(p_.x), hi2f(p_.x), lo2f(p_.y), hi2f(p_.y)};
#pragma unroll
    for (int i = 0; i < 4; i++) {
        float a = fmaf(w0[i], zl ? 0.f : xm[i],
                  fmaf(w1[i], x0[i],
                  fmaf(w2[i], zr ? 0.f : xp[i], bb[i])));
        out[i] = sigmoidf_(a);
    }
}

__global__ __launch_bounds__(512, 4) void gdn_kernel(
    const float* __restrict__ xg, const float* __restrict__ norm_g,
    const ushort_t* __restrict__ wpack,
    const float* __restrict__ qcw, const float* __restrict__ qcb,
    const float* __restrict__ kcw, const float* __restrict__ kcb,
    const float* __restrict__ vcw, const float* __restrict__ vcb,
    const float* __restrict__ qbf, const float* __restrict__ kbf,
    const float* __restrict__ vbf, const float* __restrict__ abf,
    const float* __restrict__ bbf, const float* __restrict__ pbf,
    const float* __restrict__ post_g,
    float* __restrict__ outg) {
    __shared__ __align__(16) ushort_t Xs[ROWS * LSTRIDE];   // bf16 x rows t0-1..t0+64
    __shared__ __align__(16) ushort_t Hs[ROWS * LSTRIDE];   // h; rows 1..64 become Ns
    __shared__ __align__(16) ushort_t Fq[ROWS * LSTRIDE];   // qlin; later dhat rows 0..63
    __shared__ __align__(16) ushort_t Fk[ROWS * LSTRIDE];
    __shared__ __align__(16) ushort_t Fv[ROWS * LSTRIDE];
    __shared__ __align__(16) ushort_t Fa[ROWS * LSTRIDE];
    __shared__ __align__(16) ushort_t Fb[ROWS * LSTRIDE];
    __shared__ __align__(16) float CWs[768];
    // CWs: [0..191] q taps (tap-major [3][64]); [192..383] k; [384..575] v;
    //      [576] qcb; [640] kcb; [704] vcb

    const int tid    = threadIdx.x;
    const int wave   = tid >> 6;
    const int lane   = tid & 63;
    const int cb     = (tid & 15) * 4;   // channel base (4 ch/lane)
    const int rgrp   = tid >> 4;         // 0..31
    const int bidx = blockIdx.x;
    const int b    = bidx >> 6;          // / TILES_PB (=64)
    const int tile = bidx & (TILES_PB - 1);
    const int t0   = tile * TBS;
    const bool left_edge  = (t0 == 0);
    const bool right_edge = (t0 + TBS >= T_LEN);

    f32x4 my_x[2];                       // x rows t0+rgrp, t0+rgrp+32, A -> E

    // ---- Stage A: x from global; zc_rmsnorm in-register; Xs+Hs bf16 --------
    // Main rows rgrp+1, rgrp+33 (t = t0+rgrp, t0+rgrp+32 — always in-bounds,
    // == this thread's Stage-E rows).  Halo rows 0,65 on rgrp 16,20 (waves
    // 4,5 — 3-unit Stage-B waves), Hs only (Xs unused for halo).
    {
        const f32x4 gv = *(const f32x4*)(norm_g + cb);
        auto norm_row = [&](int r, const f32x4& xv, bool wxs) {
            float s  = (xv[0] + xv[1]) + (xv[2] + xv[3]);
            float s2 = 0.f;
#pragma unroll
            for (int i = 0; i < 4; i++) s2 = fmaf(xv[i], xv[i], s2);
            s = sum16(s); s2 = sum16(s2);
            float mean = s * (1.f / 64.f);
            float var  = fmaxf(fmaf(-mean, mean, s2 * (1.f / 64.f)), 0.f);
            float inv  = rsq_(var + 1e-8f);
            if (wxs) {
                uint2 xpk; xpk.x = pk2(xv[0], xv[1]); xpk.y = pk2(xv[2], xv[3]);
                *(uint2*)(Xs + r * LSTRIDE + cb) = xpk;
            }
            uint2 hpk;
            hpk.x = pk2((xv[0] - mean) * inv * gv[0], (xv[1] - mean) * inv * gv[1]);
            hpk.y = pk2((xv[2] - mean) * inv * gv[2], (xv[3] - mean) * inv * gv[3]);
            *(uint2*)(Hs + r * LSTRIDE + cb) = hpk;
        };
#pragma unroll
        for (int ht = 0; ht < 2; ht++) {
            my_x[ht] = *(const f32x4*)(
                xg + ((size_t)b * T_LEN + t0 + rgrp + ht * 32) * DD + cb);
            norm_row(rgrp + 1 + ht * 32, my_x[ht], true);
        }
        if (rgrp == 16) {
            f32x4 xv = {0.f, 0.f, 0.f, 0.f};
            if (!left_edge)
                xv = *(const f32x4*)(xg + ((size_t)b * T_LEN + t0 - 1) * DD + cb);
            norm_row(0, xv, false);
        }
        if (rgrp == 20) {
            f32x4 xv = {0.f, 0.f, 0.f, 0.f};
            if (!right_edge)
                xv = *(const f32x4*)(xg + ((size_t)b * T_LEN + t0 + TBS) * DD + cb);
            norm_row(65, xv, false);
        }
    }
    // conv taps + biases -> CWs (tap-major)
    if (tid < 192) {
        int tap = tid >> 6, c = tid & 63;
        CWs[tid]       = qcw[c * 3 + tap];
        CWs[192 + tid] = kcw[c * 3 + tap];
        CWs[384 + tid] = vcw[c * 3 + tap];
    } else if (tid < 256) {
        int c = tid - 192;
        CWs[576 + c] = qcb[c];
        CWs[640 + c] = kcb[c];
        CWs[704 + c] = vcb[c];
    }
    __syncthreads();

    // ---- Stage B: q/k/v: 3 full m-units (m0 0,32,34) x strip per wave 0-5;
    //      a,b: 4 units on waves 6,7.  Overlapping m-units write identical
    //      values (benign).
    if (wave < 6) {
        const int g = wave >> 1, s = wave & 1;
        const ushort_t* W = wpack + g * 4096;
        const float* bias = (g == 0) ? qbf : (g == 1) ? kbf : vbf;
        ushort_t* dst     = (g == 0) ? Fq  : (g == 1) ? Fk  : Fv;
        mm32(W, bias, Hs, dst, 0,  s, lane);
        mm32(W, bias, Hs, dst, 32, s, lane);
        mm32(W, bias, Hs, dst, 34, s, lane);
    } else {
        const int s = wave & 1;
        mm32(wpack + 3 * 4096, abf, Xs, Fa, 1,  s, lane);
        mm32(wpack + 3 * 4096, abf, Xs, Fa, 33, s, lane);
        mm32(wpack + 4 * 4096, bbf, Xs, Fb, 1,  s, lane);
        mm32(wpack + 4 * 4096, bbf, Xs, Fb, 33, s, lane);
    }
    __syncthreads();

    // ---- Stage C: conv+sig (q,k,v), l2norm(q,k), delta, gate, post-norm ----
    // Two independent rows per thread (rr, rr+32) -> 2x ILP on the longest
    // dependency chain in the kernel.
#pragma unroll
    for (int half_t = 0; half_t < 2; half_t++) {
        const int rr = rgrp + 1 + half_t * 32;  // 1..32, 33..64
        const bool zl = (rr == 1) && left_edge;
        const bool zr = (rr == TBS) && right_edge;
        float qs[4], ks[4], vs[4];
        conv_sig4(CWs,       CWs + 576, cb, Fq, rr, zl, zr, qs);
        conv_sig4(CWs + 192, CWs + 640, cb, Fk, rr, zl, zr, ks);
        conv_sig4(CWs + 384, CWs + 704, cb, Fv, rr, zl, zr, vs);
        float sq = 0.f, sk = 0.f;
#pragma unroll
        for (int i = 0; i < 4; i++) {
            sq = fmaf(qs[i], qs[i], sq);
            sk = fmaf(ks[i], ks[i], sk);
        }
        float qi = rsq_(sum16(sq) + 1e-8f);
        float ki = rsq_(sum16(sk) + 1e-8f);
        uint2 av = *(const uint2*)(Fa + rr * LSTRIDE + cb);
        uint2 bv = *(const uint2*)(Fb + rr * LSTRIDE + cb);
        float af[4] = {lo2f(av.x), hi2f(av.x), lo2f(av.y), hi2f(av.y)};
        float bf[4] = {lo2f(bv.x), hi2f(bv.x), lo2f(bv.y), hi2f(bv.y)};
        float d2[4]; float sm = 0.f, sm2 = 0.f;
#pragma unroll
        for (int i = 0; i < 4; i++) {
            float delta = (qs[i] * qi) * (ks[i] * ki) * vs[i];
            d2[i] = fmaf(tanhf_(af[i]), delta, bf[i]);
            sm += d2[i];
            sm2 = fmaf(d2[i], d2[i], sm2);
        }
        sm = sum16(sm); sm2 = sum16(sm2);
        float mean = sm * (1.f / 64.f);
        float var  = fmaxf(fmaf(-mean, mean, sm2 * (1.f / 64.f)), 0.f);
        float inv  = rsq_(var + 1e-8f);
        const f32x4 pgv = *(const f32x4*)(post_g + cb);
        uint2 npk;
        npk.x = pk2((d2[0] - mean) * inv * pgv[0], (d2[1] - mean) * inv * pgv[1]);
        npk.y = pk2((d2[2] - mean) * inv * pgv[2], (d2[3] - mean) * inv * pgv[3]);
        *(uint2*)(Hs + rr * LSTRIDE + cb) = npk;   // Ns into Hs rows 1..64
    }
    __syncthreads();

    // ---- Stage D: dhat = Ns @ pw^T + pb, 16 16x16 tiles over all 8 waves ---
    // wave w: o-strip s=w&3, t-quarters h=(w>>2) and (w>>2)+2.  Output rows
    // t-rel 0..63 into Fq.
    pm16_lds(wpack + 5 * 4096, pbf, Hs, Fq, wave & 3, (wave >> 2),     lane);
    pm16_lds(wpack + 5 * 4096, pbf, Hs, Fq, wave & 3, (wave >> 2) + 2, lane);
    __syncthreads();

    // ---- Stage E: out = x + sigmoid(silu(dhat))*dhat (x from registers) ----
#pragma unroll
    for (int half_t = 0; half_t < 2; half_t++) {
        const int tr = rgrp + half_t * 32;      // t-rel 0..63
        const int t  = t0 + tr;
        uint2 dpk = *(const uint2*)(Fq + tr * LSTRIDE + cb);
        float dh[4] = {lo2f(dpk.x), hi2f(dpk.x), lo2f(dpk.y), hi2f(dpk.y)};
        f32x4 ov;
#pragma unroll
        for (int i = 0; i < 4; i++) {
            float sl = dh[i] * sigmoidf_(dh[i]);
            ov[i] = my_x[half_t][i] + sigmoidf_(sl) * dh[i];
        }
        *(f32x4*)(outg + ((size_t)b * T_LEN + t) * DD + cb) = ov;
    }
}

extern "C" void kernel_launch(void* const* d_in, const int* in_sizes, int n_in,
                              void* d_out, int out_size, void* d_ws, size_t ws_size,
                              hipStream_t stream) {
    const float* xg     = (const float*)d_in[0];
    const float* norm_g = (const float*)d_in[1];
    const float* qw  = (const float*)d_in[2];
    const float* qb  = (const float*)d_in[3];
    const float* kw  = (const float*)d_in[4];
    const float* kb  = (const float*)d_in[5];
    const float* vw  = (const float*)d_in[6];
    const float* vb  = (const float*)d_in[7];
    const float* qcw = (const float*)d_in[8];
    const float* qcb = (const float*)d_in[9];
    const float* kcw = (const float*)d_in[10];
    const float* kcb = (const float*)d_in[11];
    const float* vcw = (const float*)d_in[12];
    const float* vcb = (const float*)d_in[13];
    const float* aw  = (const float*)d_in[14];
    const float* ab  = (const float*)d_in[15];
    const float* bw  = (const float*)d_in[16];
    const float* bb  = (const float*)d_in[17];
    const float* pg  = (const float*)d_in[18];
    const float* pw  = (const float*)d_in[19];
    const float* pb  = (const float*)d_in[20];

    ushort_t* wpack = (ushort_t*)d_ws;

    hipLaunchKernelGGL(cvt_kernel, dim3(96), dim3(256), 0, stream,
                       qw, kw, vw, aw, bw, pw, wpack);

    const int B = in_sizes[0] / (T_LEN * DD);
    hipLaunchKernelGGL(gdn_kernel, dim3(B * TILES_PB), dim3(512), 0, stream,
                       xg, norm_g, wpack, qcw, qcb, kcw, kcb, vcw, vcb,
                       qb, kb, vb, ab, bb, pb, pg,
                       (float*)d_out);
}